// Round 1
// baseline (490.072 us; speedup 1.0000x reference)
//
#include <hip/hip_runtime.h>
#include <hip/hip_bf16.h>
#include <cstdint>

// ---------------------------------------------------------------------------
// SAGE GNN, 2 layers, N=50000 nodes, E=800000 edges, D: 128 -> 256 -> 128.
// Plan:
//   CSR build: deg histogram -> single-block scan -> scatter (int atomics only)
//   agg1   = mean_in(x)                      [N,128]
//   h      = relu([agg1|x] @ [[W1_l],[W1_r]] + b1)   one GEMM K=256,N=256
//   hw2    = h @ [W2_l | W2_r]               one GEMM K=256,N=256
//   out    = mean_in(hw2[:, :128]) + hw2[:,128:] + b2   (agg commutes with W2_l)
// ---------------------------------------------------------------------------

static inline size_t align_up(size_t x, size_t a) { return (x + a - 1) & ~(a - 1); }

__global__ void count_deg_kernel(const int* __restrict__ dst, int* __restrict__ deg, int E) {
  int e = blockIdx.x * blockDim.x + threadIdx.x;
  if (e < E) atomicAdd(&deg[dst[e]], 1);
}

// exclusive scan of deg[0..n) -> rowptr[0..n], single block of 1024 threads
__global__ void scan_kernel(const int* __restrict__ deg, int* __restrict__ rowptr, int n) {
  __shared__ int lds[1024];
  __shared__ int s_carry;
  const int t = threadIdx.x;
  if (t == 0) s_carry = 0;
  __syncthreads();
  for (int base = 0; base < n; base += 1024) {
    int i = base + t;
    int v = (i < n) ? deg[i] : 0;
    lds[t] = v;
    __syncthreads();
    #pragma unroll
    for (int off = 1; off < 1024; off <<= 1) {
      int add = (t >= off) ? lds[t - off] : 0;
      __syncthreads();
      lds[t] += add;
      __syncthreads();
    }
    int incl = lds[t];
    int carry = s_carry;
    if (i < n) rowptr[i] = carry + incl - v;
    __syncthreads();
    if (t == 1023) s_carry = carry + lds[1023];
    __syncthreads();
  }
  if (t == 0) rowptr[n] = s_carry;
}

__global__ void scatter_kernel(const int* __restrict__ src, const int* __restrict__ dst,
                               const int* __restrict__ rowptr, int* __restrict__ cursor,
                               int* __restrict__ col, int E) {
  int e = blockIdx.x * blockDim.x + threadIdx.x;
  if (e < E) {
    int d = dst[e];
    int p = atomicAdd(&cursor[d], 1);
    col[rowptr[d] + p] = src[e];
  }
}

// Wc[256][256]; rows 0..127 = Wa[128,256], rows 128..255 = Wb[128,256]
__global__ void concat_k_kernel(const float* __restrict__ Wa, const float* __restrict__ Wb,
                                float* __restrict__ Wc) {
  int idx = blockIdx.x * 256 + threadIdx.x;
  int k = idx >> 8, nn = idx & 255;
  Wc[idx] = (k < 128) ? Wa[(k << 8) + nn] : Wb[((k - 128) << 8) + nn];
}

// Wc[256][256]; cols 0..127 = Wa[256,128], cols 128..255 = Wb[256,128]
__global__ void concat_n_kernel(const float* __restrict__ Wa, const float* __restrict__ Wb,
                                float* __restrict__ Wc) {
  int idx = blockIdx.x * 256 + threadIdx.x;
  int k = idx >> 8, nn = idx & 255;
  Wc[idx] = (nn < 128) ? Wa[(k << 7) + nn] : Wb[(k << 7) + (nn - 128)];
}

// one wave per node; D=128 as 64 lanes x float2
__global__ void agg_mean_kernel(const float* __restrict__ x, const int* __restrict__ rowptr,
                                const int* __restrict__ col, float* __restrict__ out) {
  const int i = blockIdx.x;
  const int t = threadIdx.x;  // 0..63
  const int beg = rowptr[i], end = rowptr[i + 1];
  float2 acc = make_float2(0.f, 0.f);
  for (int e = beg; e < end; ++e) {
    int s = col[e];
    float2 v = *reinterpret_cast<const float2*>(x + ((size_t)s << 7) + (t << 1));
    acc.x += v.x;
    acc.y += v.y;
  }
  int d = end - beg;
  float inv = 1.0f / (float)(d > 1 ? d : 1);
  float2 r = make_float2(acc.x * inv, acc.y * inv);
  *reinterpret_cast<float2*>(out + ((size_t)i << 7) + (t << 1)) = r;
}

// out[i] = mean_in(hw2[:, :128]) + hw2[i, 128:] + b2
__global__ void agg2_final_kernel(const float* __restrict__ hw2, const int* __restrict__ rowptr,
                                  const int* __restrict__ col, const float* __restrict__ b2,
                                  float* __restrict__ out) {
  const int i = blockIdx.x;
  const int t = threadIdx.x;  // 0..63
  const int beg = rowptr[i], end = rowptr[i + 1];
  float2 acc = make_float2(0.f, 0.f);
  for (int e = beg; e < end; ++e) {
    int s = col[e];
    float2 v = *reinterpret_cast<const float2*>(hw2 + ((size_t)s << 8) + (t << 1));
    acc.x += v.x;
    acc.y += v.y;
  }
  int d = end - beg;
  float inv = 1.0f / (float)(d > 1 ? d : 1);
  float2 hr = *reinterpret_cast<const float2*>(hw2 + ((size_t)i << 8) + 128 + (t << 1));
  float2 bb = *reinterpret_cast<const float2*>(b2 + (t << 1));
  float2 r;
  r.x = acc.x * inv + hr.x + bb.x;
  r.y = acc.y * inv + hr.y + bb.y;
  *reinterpret_cast<float2*>(out + ((size_t)i << 7) + (t << 1)) = r;
}

// ---------------------------------------------------------------------------
// fp32 GEMM: C[M,256-wide tiles] = Aconcat @ B (+bias, relu).
// A is the virtual K-concat of A1[M,lda1] (first K1 cols) and A2[M,lda2].
// B is [Ktot,256] row-major. BM=64, BN=64, BK=32, 256 threads, 4x4/thread.
// ---------------------------------------------------------------------------
#define BM 64
#define BN 64
#define BK 32

template <bool RELU_BIAS>
__global__ __launch_bounds__(256) void gemm_kernel(
    const float* __restrict__ A1, int lda1, int K1,
    const float* __restrict__ A2, int lda2,
    const float* __restrict__ B, const float* __restrict__ bias,
    float* __restrict__ C, int ldc, int M, int Ktot) {
  __shared__ float As[BK][BM + 4];  // transposed: As[k][m]
  __shared__ float Bs[BK][BN + 4];
  const int t = threadIdx.x;
  const int bm = blockIdx.x * BM;
  const int bn = blockIdx.y * BN;
  const int tx = t & 15;        // col group
  const int ty = t >> 4;        // row group
  const int a_row = t >> 3;     // 0..31
  const int a_k4 = (t & 7) << 2;  // 0,4,...,28
  const int b_k = t >> 4;       // 0..15
  const int b_n4 = (t & 15) << 2;

  float acc[4][4] = {{0.f}};

  for (int k0 = 0; k0 < Ktot; k0 += BK) {
    // stage A (64 rows x 32 k), 128B-contiguous per row per 8 lanes
    #pragma unroll
    for (int rr = 0; rr < 2; ++rr) {
      const int gm = bm + a_row + rr * 32;
      const int gk = k0 + a_k4;
      float4 av = make_float4(0.f, 0.f, 0.f, 0.f);
      if (gm < M) {
        const float* s = (gk < K1) ? (A1 + (size_t)gm * lda1 + gk)
                                   : (A2 + (size_t)gm * lda2 + (gk - K1));
        av = *reinterpret_cast<const float4*>(s);
      }
      As[a_k4 + 0][a_row + rr * 32] = av.x;
      As[a_k4 + 1][a_row + rr * 32] = av.y;
      As[a_k4 + 2][a_row + rr * 32] = av.z;
      As[a_k4 + 3][a_row + rr * 32] = av.w;
    }
    // stage B (32 k x 64 n)
    #pragma unroll
    for (int rr = 0; rr < 2; ++rr) {
      const int gk = k0 + b_k + rr * 16;
      float4 bv = *reinterpret_cast<const float4*>(B + (size_t)gk * 256 + bn + b_n4);
      *reinterpret_cast<float4*>(&Bs[b_k + rr * 16][b_n4]) = bv;
    }
    __syncthreads();
    #pragma unroll
    for (int kk = 0; kk < BK; ++kk) {
      float4 a = *reinterpret_cast<const float4*>(&As[kk][ty << 2]);
      float4 b = *reinterpret_cast<const float4*>(&Bs[kk][tx << 2]);
      float ar[4] = {a.x, a.y, a.z, a.w};
      float br[4] = {b.x, b.y, b.z, b.w};
      #pragma unroll
      for (int i = 0; i < 4; ++i)
        #pragma unroll
        for (int j = 0; j < 4; ++j)
          acc[i][j] += ar[i] * br[j];
    }
    __syncthreads();
  }

  const int row = bm + (ty << 2);
  const int colb = bn + (tx << 2);
  float4 bb = make_float4(0.f, 0.f, 0.f, 0.f);
  if (RELU_BIAS) bb = *reinterpret_cast<const float4*>(bias + colb);
  #pragma unroll
  for (int i = 0; i < 4; ++i) {
    if (row + i < M) {
      float4 v = make_float4(acc[i][0], acc[i][1], acc[i][2], acc[i][3]);
      if (RELU_BIAS) {
        v.x = fmaxf(v.x + bb.x, 0.f);
        v.y = fmaxf(v.y + bb.y, 0.f);
        v.z = fmaxf(v.z + bb.z, 0.f);
        v.w = fmaxf(v.w + bb.w, 0.f);
      }
      *reinterpret_cast<float4*>(C + (size_t)(row + i) * ldc + colb) = v;
    }
  }
}

extern "C" void kernel_launch(void* const* d_in, const int* in_sizes, int n_in,
                              void* d_out, int out_size, void* d_ws, size_t ws_size,
                              hipStream_t stream) {
  const float* x    = (const float*)d_in[0];
  const int*   edge = (const int*)d_in[1];
  const float* W1_l = (const float*)d_in[2];
  const float* b1   = (const float*)d_in[3];
  const float* W1_r = (const float*)d_in[4];
  const float* W2_l = (const float*)d_in[5];
  const float* b2   = (const float*)d_in[6];
  const float* W2_r = (const float*)d_in[7];
  float* out = (float*)d_out;

  const int N = in_sizes[0] / 128;
  const int E = in_sizes[1] / 2;
  const int* srcv = edge;
  const int* dstv = edge + E;

  char* ws = (char*)d_ws;
  size_t off = 0;
  auto alloc = [&](size_t bytes) -> void* {
    void* p = ws + off;
    off += align_up(bytes, 256);
    return p;
  };
  int* deg    = (int*)alloc((size_t)N * 4);
  int* cursor = (int*)alloc((size_t)N * 4);
  int* rowptr = (int*)alloc((size_t)(N + 1) * 4);
  int* col    = (int*)alloc((size_t)E * 4);
  float* Wc1  = (float*)alloc(256 * 256 * 4);
  float* Wc2  = (float*)alloc(256 * 256 * 4);
  float* h    = (float*)alloc((size_t)N * 256 * 4);
  float* hw2  = (float*)alloc((size_t)N * 256 * 4);
  // agg1 [N,128] aliases hw2: dead before gemm2 writes hw2
  float* agg1 = hw2;

  hipMemsetAsync(deg, 0, (size_t)N * 4, stream);
  hipMemsetAsync(cursor, 0, (size_t)N * 4, stream);

  concat_k_kernel<<<256, 256, 0, stream>>>(W1_l, W1_r, Wc1);
  concat_n_kernel<<<256, 256, 0, stream>>>(W2_l, W2_r, Wc2);

  const int eb = (E + 255) / 256;
  count_deg_kernel<<<eb, 256, 0, stream>>>(dstv, deg, E);
  scan_kernel<<<1, 1024, 0, stream>>>(deg, rowptr, N);
  scatter_kernel<<<eb, 256, 0, stream>>>(srcv, dstv, rowptr, cursor, col, E);

  agg_mean_kernel<<<N, 64, 0, stream>>>(x, rowptr, col, agg1);

  dim3 gemm_grid((N + BM - 1) / BM, 256 / BN);
  // h = relu([agg1 | x] @ Wc1 + b1)
  gemm_kernel<true><<<gemm_grid, 256, 0, stream>>>(agg1, 128, 128, x, 128, Wc1, b1, h, 256, N, 256);
  // hw2 = h @ [W2_l | W2_r]
  gemm_kernel<false><<<gemm_grid, 256, 0, stream>>>(h, 256, 256, nullptr, 0, Wc2, nullptr, hw2, 256, N, 256);

  agg2_final_kernel<<<N, 64, 0, stream>>>(hw2, rowptr, col, b2, out);
}

// Round 2
// 215.353 us; speedup vs baseline: 2.2757x; 2.2757x over previous
//
#include <hip/hip_runtime.h>
#include <hip/hip_bf16.h>
#include <cstdint>

// ---------------------------------------------------------------------------
// SAGE GNN, 2 layers, N=50000, E=800000, D: 128 -> 256 -> 128.
//   CSR build: deg histogram -> hierarchical scan -> scatter (int atomics only)
//   A1[:,128:256] = bf16(x)            (convert kernel)
//   A1[:,0:128]   = mean_in(bf16 x)    (agg1, one wave/node, fp32 accum)
//   h   = relu(A1 @ [[W1_l],[W1_r]] + b1)      bf16 MFMA GEMM, K=256,N=256
//   hw2 = h @ [W2_l | W2_r]                    bf16 MFMA GEMM
//   out = mean_in(hw2[:,:128]) + hw2[:,128:] + b2   (agg commutes with W2_l)
// ---------------------------------------------------------------------------

static inline size_t align_up(size_t x, size_t a) { return (x + a - 1) & ~(a - 1); }

using short8 = __attribute__((ext_vector_type(8))) short;
using f32x4  = __attribute__((ext_vector_type(4))) float;

__device__ __forceinline__ float bfpair_lo(unsigned int v) {
  union { unsigned int i; float f; } u; u.i = v << 16; return u.f;
}
__device__ __forceinline__ float bfpair_hi(unsigned int v) {
  union { unsigned int i; float f; } u; u.i = v & 0xffff0000u; return u.f;
}
__device__ __forceinline__ unsigned short f2bf(float f) {
  union { float f; unsigned int i; } u; u.f = f;
  unsigned int r = u.i + 0x7fffu + ((u.i >> 16) & 1u);
  return (unsigned short)(r >> 16);
}

__device__ __forceinline__ void gload_lds16(const void* g, void* l) {
  __builtin_amdgcn_global_load_lds(
      (const __attribute__((address_space(1))) void*)g,
      (__attribute__((address_space(3))) void*)l, 16, 0, 0);
}

// ------------------------------- CSR build ---------------------------------

__global__ void count_deg_kernel(const int* __restrict__ dst, int* __restrict__ deg, int E) {
  int e = blockIdx.x * blockDim.x + threadIdx.x;
  if (e < E) atomicAdd(&deg[dst[e]], 1);
}

// per-1024-segment sums (256 threads x int4)
__global__ void scan_part1(const int* __restrict__ deg, int* __restrict__ bsum, int n) {
  int b = blockIdx.x, t = threadIdx.x;
  int base = b * 1024 + t * 4;
  int4 v = make_int4(0, 0, 0, 0);
  if (base < n) v = *reinterpret_cast<const int4*>(deg + base);
  int s = v.x + v.y + v.z + v.w;
  #pragma unroll
  for (int off = 1; off < 64; off <<= 1) s += __shfl_xor(s, off, 64);
  __shared__ int ws_[4];
  if ((t & 63) == 0) ws_[t >> 6] = s;
  __syncthreads();
  if (t == 0) bsum[b] = ws_[0] + ws_[1] + ws_[2] + ws_[3];
}

// single wave: exclusive-scan nb (<=64) block sums in place; rowptr[n] = total
__global__ void scan_part2(int* __restrict__ bsum, int* __restrict__ rowptr, int nb, int n) {
  int t = threadIdx.x;  // 64
  int v = (t < nb) ? bsum[t] : 0;
  int inc = v;
  #pragma unroll
  for (int off = 1; off < 64; off <<= 1) {
    int u = __shfl_up(inc, off, 64);
    if (t >= off) inc += u;
  }
  if (t < nb) bsum[t] = inc - v;
  if (t == 63) rowptr[n] = inc;
}

// per-segment exclusive scan + segment offset -> rowptr
__global__ void scan_part3(const int* __restrict__ deg, const int* __restrict__ bsum,
                           int* __restrict__ rowptr, int n) {
  int b = blockIdx.x, t = threadIdx.x;  // 256
  int base = b * 1024 + t * 4;
  int4 v = make_int4(0, 0, 0, 0);
  if (base < n) v = *reinterpret_cast<const int4*>(deg + base);
  int tsum = v.x + v.y + v.z + v.w;
  int lane = t & 63, w = t >> 6;
  int inc = tsum;
  #pragma unroll
  for (int off = 1; off < 64; off <<= 1) {
    int u = __shfl_up(inc, off, 64);
    if (lane >= off) inc += u;
  }
  __shared__ int wsum[4];
  if (lane == 63) wsum[w] = inc;
  __syncthreads();
  int woff = bsum[b];
  for (int i = 0; i < w; ++i) woff += wsum[i];
  if (base < n) {
    int e0 = woff + inc - tsum;
    int4 r;
    r.x = e0;
    r.y = e0 + v.x;
    r.z = e0 + v.x + v.y;
    r.w = e0 + v.x + v.y + v.z;
    *reinterpret_cast<int4*>(rowptr + base) = r;
  }
}

__global__ void scatter_kernel(const int* __restrict__ src, const int* __restrict__ dst,
                               const int* __restrict__ rowptr, int* __restrict__ cursor,
                               int* __restrict__ col, int E) {
  int e = blockIdx.x * blockDim.x + threadIdx.x;
  if (e < E) {
    int d = dst[e];
    int p = atomicAdd(&cursor[d], 1);
    col[rowptr[d] + p] = src[e];
  }
}

// ------------------------- weight prep (bf16, transposed) ------------------

// BT1[n][k], n,k in [0,256): k<128 -> W1_l[k][n] ; k>=128 -> W1_r[k-128][n]
__global__ void build_bt1(const float* __restrict__ W1l, const float* __restrict__ W1r,
                          __hip_bfloat16* __restrict__ BT) {
  int idx = blockIdx.x * 256 + threadIdx.x;
  int n = idx >> 8, k = idx & 255;
  float v = (k < 128) ? W1l[k * 256 + n] : W1r[(k - 128) * 256 + n];
  BT[idx] = __float2bfloat16(v);
}

// BT2[n][k]: n<128 -> W2_l[k][n] ; n>=128 -> W2_r[k][n-128]   (k in [0,256))
__global__ void build_bt2(const float* __restrict__ W2l, const float* __restrict__ W2r,
                          __hip_bfloat16* __restrict__ BT) {
  int idx = blockIdx.x * 256 + threadIdx.x;
  int n = idx >> 8, k = idx & 255;
  float v = (n < 128) ? W2l[k * 128 + n] : W2r[k * 128 + (n - 128)];
  BT[idx] = __float2bfloat16(v);
}

// A1[i][128+j] = bf16(x[i][j]); thread handles 4 consecutive j
__global__ void convert_x_kernel(const float* __restrict__ x, __hip_bfloat16* __restrict__ A1,
                                 int total4) {
  int idx = blockIdx.x * blockDim.x + threadIdx.x;
  if (idx >= total4) return;
  int i = idx >> 5, j4 = (idx & 31) << 2;
  float4 v = *reinterpret_cast<const float4*>(x + (size_t)i * 128 + j4);
  unsigned int p0 = ((unsigned)f2bf(v.y) << 16) | f2bf(v.x);
  unsigned int p1 = ((unsigned)f2bf(v.w) << 16) | f2bf(v.z);
  uint2 pk = make_uint2(p0, p1);
  *reinterpret_cast<uint2*>(A1 + (size_t)i * 256 + 128 + j4) = pk;
}

// ------------------------------ aggregations -------------------------------

// A1[i][0:128] = mean over in-neighbors of A1[s][128:256]  (bf16 in/out, fp32 acc)
__global__ __launch_bounds__(64) void agg1_kernel(const int* __restrict__ rowptr,
                                                  const int* __restrict__ col,
                                                  __hip_bfloat16* __restrict__ A1) {
  const int i = blockIdx.x;
  const int t = threadIdx.x;  // 0..63
  const int beg = rowptr[i], end = rowptr[i + 1];
  float ax = 0.f, ay = 0.f;
  int e = beg;
  for (; e + 1 < end; e += 2) {
    int s0 = col[e], s1 = col[e + 1];
    unsigned int v0 = *reinterpret_cast<const unsigned int*>(A1 + (size_t)s0 * 256 + 128 + t * 2);
    unsigned int v1 = *reinterpret_cast<const unsigned int*>(A1 + (size_t)s1 * 256 + 128 + t * 2);
    ax += bfpair_lo(v0) + bfpair_lo(v1);
    ay += bfpair_hi(v0) + bfpair_hi(v1);
  }
  if (e < end) {
    int s0 = col[e];
    unsigned int v0 = *reinterpret_cast<const unsigned int*>(A1 + (size_t)s0 * 256 + 128 + t * 2);
    ax += bfpair_lo(v0);
    ay += bfpair_hi(v0);
  }
  int d = end - beg;
  float inv = 1.0f / (float)(d > 1 ? d : 1);
  unsigned int pk = ((unsigned)f2bf(ay * inv) << 16) | f2bf(ax * inv);
  *reinterpret_cast<unsigned int*>(A1 + (size_t)i * 256 + t * 2) = pk;
}

// out[i] = mean_in(hw2[:,:128]) + hw2[i,128:] + b2   (fp32 out)
__global__ __launch_bounds__(64) void agg2_kernel(const __hip_bfloat16* __restrict__ hw2,
                                                  const int* __restrict__ rowptr,
                                                  const int* __restrict__ col,
                                                  const float* __restrict__ b2,
                                                  float* __restrict__ out) {
  const int i = blockIdx.x;
  const int t = threadIdx.x;  // 0..63
  const int beg = rowptr[i], end = rowptr[i + 1];
  float ax = 0.f, ay = 0.f;
  int e = beg;
  for (; e + 1 < end; e += 2) {
    int s0 = col[e], s1 = col[e + 1];
    unsigned int v0 = *reinterpret_cast<const unsigned int*>(hw2 + (size_t)s0 * 256 + t * 2);
    unsigned int v1 = *reinterpret_cast<const unsigned int*>(hw2 + (size_t)s1 * 256 + t * 2);
    ax += bfpair_lo(v0) + bfpair_lo(v1);
    ay += bfpair_hi(v0) + bfpair_hi(v1);
  }
  if (e < end) {
    int s0 = col[e];
    unsigned int v0 = *reinterpret_cast<const unsigned int*>(hw2 + (size_t)s0 * 256 + t * 2);
    ax += bfpair_lo(v0);
    ay += bfpair_hi(v0);
  }
  int d = end - beg;
  float inv = 1.0f / (float)(d > 1 ? d : 1);
  unsigned int sv = *reinterpret_cast<const unsigned int*>(hw2 + (size_t)i * 256 + 128 + t * 2);
  float2 bb = *reinterpret_cast<const float2*>(b2 + t * 2);
  float2 r;
  r.x = ax * inv + bfpair_lo(sv) + bb.x;
  r.y = ay * inv + bfpair_hi(sv) + bb.y;
  *reinterpret_cast<float2*>(out + (size_t)i * 128 + t * 2) = r;
}

// ------------------------------ MFMA GEMM ----------------------------------
// C[M,256] = A[M,256] @ B[256,256] (+bias, relu), all bf16, fp32 accum.
// BT is B transposed: BT[n][k]. Tile 128x128, BK=32, 256 thr (4 waves, 2x2),
// per-wave 64x64 = 4x4 fragments of 16x16x32. global_load_lds width 16.
template <bool BIAS_RELU>
__global__ __launch_bounds__(256) void mfma_gemm_kernel(
    const __hip_bfloat16* __restrict__ A,   // [M][256]
    const __hip_bfloat16* __restrict__ BT,  // [256][256]
    const float* __restrict__ bias,         // [256] or null
    __hip_bfloat16* __restrict__ C,         // [M][256]
    int M) {
  __shared__ __hip_bfloat16 As[128 * 32];
  __shared__ __hip_bfloat16 Bs[128 * 32];
  const int t = threadIdx.x;
  const int lane = t & 63;
  const int w = t >> 6;
  const int bm = blockIdx.x * 128;
  const int bn = blockIdx.y * 128;
  const int wr = (w >> 1) * 64;  // wave row offset in tile
  const int wc = (w & 1) * 64;   // wave col offset

  // staging: chunk c (0..7) covers rows [c*16, c*16+16) x 64B; wave w owns
  // chunks {2w, 2w+1}; lane l -> row c*16 + (l>>2), 16B slot l&3.
  const int srow = lane >> 2;
  const int sbyte = (lane & 3) * 16;

  f32x4 acc[4][4];
  #pragma unroll
  for (int i = 0; i < 4; ++i)
    #pragma unroll
    for (int j = 0; j < 4; ++j) acc[i][j] = (f32x4)(0.f);

  const int frow_a = wr + (lane & 15);
  const int frow_b = wc + (lane & 15);
  const int fbyte = (lane >> 4) * 16;  // k-slot byte offset within 64B row

  for (int k0 = 0; k0 < 256; k0 += 32) {
    #pragma unroll
    for (int q = 0; q < 2; ++q) {
      const int chunk = w * 2 + q;
      const int row = chunk * 16 + srow;
      int gr = bm + row;
      if (gr >= M) gr = M - 1;
      gload_lds16((const char*)A + (size_t)gr * 512 + k0 * 2 + sbyte,
                  (char*)As + chunk * 1024);
      gload_lds16((const char*)BT + (size_t)(bn + row) * 512 + k0 * 2 + sbyte,
                  (char*)Bs + chunk * 1024);
    }
    __syncthreads();
    short8 af[4], bf[4];
    #pragma unroll
    for (int i = 0; i < 4; ++i) {
      af[i] = *reinterpret_cast<const short8*>((const char*)As + (frow_a + i * 16) * 64 + fbyte);
      bf[i] = *reinterpret_cast<const short8*>((const char*)Bs + (frow_b + i * 16) * 64 + fbyte);
    }
    #pragma unroll
    for (int i = 0; i < 4; ++i)
      #pragma unroll
      for (int j = 0; j < 4; ++j)
        acc[i][j] = __builtin_amdgcn_mfma_f32_16x16x32_bf16(af[i], bf[j], acc[i][j], 0, 0, 0);
    __syncthreads();
  }

  // epilogue: C fragment layout col = lane&15, row = (lane>>4)*4 + q
  const int crow0 = bm + wr + (lane >> 4) * 4;
  const int ccol0 = bn + wc + (lane & 15);
  float bj[4] = {0.f, 0.f, 0.f, 0.f};
  if (BIAS_RELU) {
    #pragma unroll
    for (int j = 0; j < 4; ++j) bj[j] = bias[ccol0 + j * 16];
  }
  #pragma unroll
  for (int i = 0; i < 4; ++i) {
    #pragma unroll
    for (int q = 0; q < 4; ++q) {
      const int r = crow0 + i * 16 + q;
      if (r < M) {
        #pragma unroll
        for (int j = 0; j < 4; ++j) {
          float v = acc[i][j][q];
          if (BIAS_RELU) v = fmaxf(v + bj[j], 0.f);
          C[(size_t)r * 256 + ccol0 + j * 16] = __float2bfloat16(v);
        }
      }
    }
  }
}

// ------------------------------ launcher -----------------------------------

extern "C" void kernel_launch(void* const* d_in, const int* in_sizes, int n_in,
                              void* d_out, int out_size, void* d_ws, size_t ws_size,
                              hipStream_t stream) {
  const float* x    = (const float*)d_in[0];
  const int*   edge = (const int*)d_in[1];
  const float* W1_l = (const float*)d_in[2];
  const float* b1   = (const float*)d_in[3];
  const float* W1_r = (const float*)d_in[4];
  const float* W2_l = (const float*)d_in[5];
  const float* b2   = (const float*)d_in[6];
  const float* W2_r = (const float*)d_in[7];
  float* out = (float*)d_out;

  const int N = in_sizes[0] / 128;
  const int E = in_sizes[1] / 2;
  const int* srcv = edge;
  const int* dstv = edge + E;

  char* ws = (char*)d_ws;
  size_t off = 0;
  auto alloc = [&](size_t bytes) -> void* {
    void* p = ws + off;
    off += align_up(bytes, 256);
    return p;
  };
  int* deg    = (int*)alloc((size_t)N * 4);
  int* cursor = (int*)alloc((size_t)N * 4);
  int* rowptr = (int*)alloc((size_t)(N + 1) * 4);
  int* bsum   = (int*)alloc(64 * 4);
  int* col    = (int*)alloc((size_t)E * 4);
  __hip_bfloat16* BT1 = (__hip_bfloat16*)alloc(256 * 256 * 2);
  __hip_bfloat16* BT2 = (__hip_bfloat16*)alloc(256 * 256 * 2);
  __hip_bfloat16* A1  = (__hip_bfloat16*)alloc((size_t)N * 256 * 2);
  __hip_bfloat16* h   = (__hip_bfloat16*)alloc((size_t)N * 256 * 2);
  __hip_bfloat16* hw2 = (__hip_bfloat16*)alloc((size_t)N * 256 * 2);

  hipMemsetAsync(deg, 0, (size_t)N * 4, stream);
  hipMemsetAsync(cursor, 0, (size_t)N * 4, stream);

  build_bt1<<<256, 256, 0, stream>>>(W1_l, W1_r, BT1);
  build_bt2<<<256, 256, 0, stream>>>(W2_l, W2_r, BT2);
  convert_x_kernel<<<(N * 32 + 255) / 256, 256, 0, stream>>>(x, A1, N * 32);

  const int eb = (E + 255) / 256;
  count_deg_kernel<<<eb, 256, 0, stream>>>(dstv, deg, E);
  const int nb = (N + 1023) / 1024;  // 49 (<=64 required by scan_part2)
  scan_part1<<<nb, 256, 0, stream>>>(deg, bsum, N);
  scan_part2<<<1, 64, 0, stream>>>(bsum, rowptr, nb, N);
  scan_part3<<<nb, 256, 0, stream>>>(deg, bsum, rowptr, N);
  scatter_kernel<<<eb, 256, 0, stream>>>(srcv, dstv, rowptr, cursor, col, E);

  agg1_kernel<<<N, 64, 0, stream>>>(rowptr, col, A1);

  dim3 gemm_grid((N + 127) / 128, 2);
  mfma_gemm_kernel<true><<<gemm_grid, 256, 0, stream>>>(A1, BT1, b1, h, N);
  mfma_gemm_kernel<false><<<gemm_grid, 256, 0, stream>>>(h, BT2, nullptr, hw2, N);

  agg2_kernel<<<N, 64, 0, stream>>>(hw2, rowptr, col, b2, out);
}